// Round 8
// baseline (149.035 us; speedup 1.0000x reference)
//
#include <hip/hip_runtime.h>
#include <hip/hip_bf16.h>
#include <cstdint>
#include <cstddef>

// SetConvDecoder on MI355X (gfx950).
// out[b,t,c] = (1/128) * sum_g exp(-0.5*||(xt[b,t]-xg[b,g])/ls||^2) * zg[b,g,c]
// B=4, NT=2048, NG=16384, DZ=128, DX=2.
//
// Round-8: occupancy attack. R5 measured 57us with 232 regs/wave -> 2
// waves/SIMD cap; ~65% stall cycles. Now: 32-row waves (acc=64 VGPR),
// __launch_bounds__(128,4) -> 4 waves/SIMD, 8 independent 2-wave blocks/CU.
//   grid 1024 = b4 x mt32 x ksp8 (XCD-swizzled). Ring-4 LDS (17KB/block),
//   prefetch depth 3, uniform 3 loads/wave/iter -> counted vmcnt(6).
//   Per-tile triplets ride the ring (192B/tile). Epilogue: plain coalesced
//   fp32 partial stores (8 slices) + reduce kernel; atomic fallback if ws
//   too small.

typedef float  f32x4  __attribute__((ext_vector_type(4)));
typedef float  f32x16 __attribute__((ext_vector_type(16)));
typedef short  short8 __attribute__((ext_vector_type(8)));
typedef unsigned short ushort4v __attribute__((ext_vector_type(4)));
typedef unsigned short ushort8 __attribute__((ext_vector_type(8)));

#if __has_builtin(__builtin_amdgcn_exp2f)
#define EXP2F(x) __builtin_amdgcn_exp2f(x)
#else
#define EXP2F(x) exp2f(x)
#endif

#define AS1C(p) ((const __attribute__((address_space(1))) void*)(p))
#define AS3(p)  ((__attribute__((address_space(3))) void*)(p))

__device__ __forceinline__ unsigned short bf16_bits(float f) {
  __bf16 h = (__bf16)f;
  return __builtin_bit_cast(unsigned short, h);
}

// ---------------------------------------------------------------------------
// Pre-kernel (unchanged): 1024 blocks (b4 x 256 groups of 64 g) x 256 thr.
// zg -> bf16*(1/128) in per-16k-tile fragment layout via LDS transpose;
// xg triplets (2u0,2u1,-|u|^2) 12B/g; xt (u0,u1,-|u|^2,0) 16B/row;
// u = x * sqrt(0.5*log2 e) / ls.
// ---------------------------------------------------------------------------
__global__ __launch_bounds__(256) void pre_kernel(
    const float* __restrict__ x_grid, const float* __restrict__ z_grid,
    const float* __restrict__ xt, const float* __restrict__ lsp,
    unsigned short* __restrict__ zgb, float* __restrict__ xg_trip,
    float* __restrict__ xt4)
{
  __shared__ unsigned short lt[64 * 128];   // 16 KB row-major [row][c]
  const int bid = blockIdx.x;
  const int b   = bid >> 8;
  const int grp = bid & 255;
  const int tid = threadIdx.x;
  const size_t gbase = (size_t)b * 16384 + grp * 64;
  const float sc = 1.0f / 128.0f;

  const float* zr = z_grid + gbase * 128;
  #pragma unroll
  for (int it = 0; it < 8; ++it) {
    const int idx = it * 256 + tid;
    const int row = idx >> 5, c4 = idx & 31;
    f32x4 v = *(const f32x4*)(zr + row * 128 + c4 * 4);
    ushort4v o;
    o.x = bf16_bits(v.x * sc); o.y = bf16_bits(v.y * sc);
    o.z = bf16_bits(v.z * sc); o.w = bf16_bits(v.w * sc);
    *(ushort4v*)(lt + row * 128 + c4 * 4) = o;
  }

  if (tid < 128) {
    const float ls0 = 1e-5f + log1pf(expf(lsp[0]));
    const float ls1 = 1e-5f + log1pf(expf(lsp[1]));
    const float cs  = sqrtf(0.7213475204444817f);   // sqrt(0.5*log2 e)
    const float s0 = cs / ls0, s1 = cs / ls1;
    if (tid < 64) {
      const size_t g = gbase + tid;
      const float u0 = x_grid[g * 2 + 0] * s0;
      const float u1 = x_grid[g * 2 + 1] * s1;
      float* d = xg_trip + g * 3;
      d[0] = 2.0f * u0; d[1] = 2.0f * u1; d[2] = -(u0 * u0 + u1 * u1);
    } else if (bid < 128) {
      const int bx = bid >> 5;
      const int r  = (bid & 31) * 64 + (tid - 64);
      const float u0 = xt[((size_t)(bx * 2048 + r)) * 2 + 0] * s0;
      const float u1 = xt[((size_t)(bx * 2048 + r)) * 2 + 1] * s1;
      f32x4 d; d.x = u0; d.y = u1; d.z = -(u0 * u0 + u1 * u1); d.w = 0.0f;
      *(f32x4*)(xt4 + ((size_t)(bx * 2048 + r)) * 4) = d;
    }
  }

  __syncthreads();

  const int q2p = tid >> 7, c = tid & 127;
  #pragma unroll
  for (int h = 0; h < 4; ++h) {            // 4 16-k tiles per block
    ushort8 o;
    #pragma unroll
    for (int hi = 0; hi < 2; ++hi)
      #pragma unroll
      for (int j = 0; j < 4; ++j)
        o[hi * 4 + j] = lt[(h * 16 + 4 * q2p + 8 * hi + j) * 128 + c];
    *(ushort8*)(zgb + ((size_t)(b * 1024 + grp * 4 + h)) * 2048
                    + (size_t)(q2p * 128 + c) * 8) = o;
  }
}

// ---------------------------------------------------------------------------
// Main kernel: 1024 blocks (b4 x mt32 x ksp8, XCD-swizzled) x 128 thr
// (2 waves of 32 rows each). LDS 17408 B: ring[4][4096] zg + trg[4][256].
// ---------------------------------------------------------------------------
__global__ __launch_bounds__(128, 4) void main_kernel(
    const unsigned short* __restrict__ zgb,
    const float* __restrict__ xg_trip,
    const float* __restrict__ xt4,
    float* __restrict__ out,
    float* __restrict__ partials)     // nullptr -> atomic fallback
{
  __shared__ __align__(128) char smem[4 * 4096 + 4 * 256];
  char* ring = smem;                  // [4][4096] zg tiles
  char* trg  = smem + 16384;          // [4][256]  xg triplets (192 used)

  const int raw = blockIdx.x;
  const int lid = (raw & 7) * 128 + (raw >> 3);   // bijective XCD swizzle
  const int mt  = lid & 31;
  const int b   = (lid >> 5) & 3;
  const int ksp = lid >> 7;                       // 0..7

  const int tid = threadIdx.x;
  const int w   = tid >> 6;           // wave: 32-row sub-tile
  const int l   = tid & 63;
  const int l31 = l & 31;
  const int q2  = l >> 5;

  // xt triplet for this lane's single row (constant over the loop)
  const int r = mt * 64 + w * 32 + l31;
  f32x4 tv = *(const f32x4*)(xt4 + ((size_t)(b * 2048 + r)) * 4);
  const float at0 = tv.x, at1 = tv.y, ca = tv.z;

  f32x16 acc[4];
  #pragma unroll
  for (int ni = 0; ni < 4; ++ni)
    #pragma unroll
    for (int e = 0; e < 16; ++e)
      acc[ni][e] = 0.0f;

  // this block's 128 sequential 16-k tiles
  const char* zsrc = (const char*)zgb + ((size_t)(b * 1024 + ksp * 128)) * 4096;
  const char* tsrc = (const char*)xg_trip + ((size_t)(b * 16384 + ksp * 2048)) * 12;

  auto stage = [&](int s) {           // 3 gl_lds per wave, every iter
    const int sl = s & 3;
    const char* zs = zsrc + (size_t)s * 4096 + w * 2048;
    char* zd = ring + sl * 4096 + w * 2048;
    __builtin_amdgcn_global_load_lds(AS1C(zs + l * 16), AS3(zd + l * 16), 16, 0, 0);
    __builtin_amdgcn_global_load_lds(AS1C(zs + 1024 + l * 16),
                                     AS3(zd + 1024 + l * 16), 16, 0, 0);
    if (l < 6) {                      // 96B of triplets per wave
      __builtin_amdgcn_global_load_lds(
          AS1C(tsrc + (size_t)s * 192 + w * 96 + l * 16),
          AS3(trg + sl * 256 + w * 96 + l * 16), 16, 0, 0);
    }
  };

  stage(0);
  stage(1);
  stage(2);

  #pragma unroll 4
  for (int s = 0; s < 128; ++s) {
    // wait for tile s's 3 loads; keep tiles s+1,s+2 (6 loads) in flight
    if (s < 126) { asm volatile("s_waitcnt vmcnt(6)" ::: "memory"); }
    else         { asm volatile("s_waitcnt vmcnt(0)" ::: "memory"); }
    __builtin_amdgcn_s_barrier();     // 2-wave rendezvous
    asm volatile("" ::: "memory");

    if (s + 3 < 128) stage(s + 3);    // slot (s+3)&3 was last read at s-1

    // xg triplets for this lane's 8 k's: k16 = 4*q2 + j (+8 for hi half)
    const float* tb = (const float*)(trg + (s & 3) * 256 + q2 * 48);
    f32x4 L0 = *(const f32x4*)(tb + 0);
    f32x4 L1 = *(const f32x4*)(tb + 4);
    f32x4 L2 = *(const f32x4*)(tb + 8);
    f32x4 H0 = *(const f32x4*)(tb + 24);
    f32x4 H1 = *(const f32x4*)(tb + 28);
    f32x4 H2 = *(const f32x4*)(tb + 32);
    float g0[8], g1[8], cb[8];
    g0[0]=L0.x; g1[0]=L0.y; cb[0]=L0.z;
    g0[1]=L0.w; g1[1]=L1.x; cb[1]=L1.y;
    g0[2]=L1.z; g1[2]=L1.w; cb[2]=L2.x;
    g0[3]=L2.y; g1[3]=L2.z; cb[3]=L2.w;
    g0[4]=H0.x; g1[4]=H0.y; cb[4]=H0.z;
    g0[5]=H0.w; g1[5]=H1.x; cb[5]=H1.y;
    g0[6]=H1.z; g1[6]=H1.w; cb[6]=H2.x;
    g0[7]=H2.y; g1[7]=H2.z; cb[7]=H2.w;

    // A-fragment (RBF weights) in registers: 8 weights for row r
    union { short8 s8; __bf16 e[8]; } u;
    #pragma unroll
    for (int j = 0; j < 8; ++j) {
      float arg = __builtin_fmaf(at0, g0[j],
                  __builtin_fmaf(at1, g1[j], ca + cb[j]));
      u.e[j] = (__bf16)EXP2F(arg);
    }
    const short8 af = u.s8;

    // B-fragments: contiguous 16B/lane, conflict-free
    const char* zt = ring + (s & 3) * 4096 + q2 * 2048 + l31 * 16;
    #pragma unroll
    for (int ni = 0; ni < 4; ++ni) {
      short8 bfr = *(const short8*)(zt + ni * 512);
      acc[ni] = __builtin_amdgcn_mfma_f32_32x32x16_bf16(af, bfr, acc[ni], 0, 0, 0);
    }
  }

  // epilogue: plain coalesced partial stores (zg pre-scaled by 1/128)
  if (partials) {
    float* pb = partials + (size_t)ksp * 1048576
              + ((size_t)(b * 2048 + mt * 64 + w * 32)) * 128;
    #pragma unroll
    for (int ni = 0; ni < 4; ++ni)
      #pragma unroll
      for (int rr = 0; rr < 16; ++rr) {
        const int row = (rr & 3) + 8 * (rr >> 2) + 4 * q2;  // verified C/D map
        pb[row * 128 + ni * 32 + l31] = acc[ni][rr];
      }
  } else {
    #pragma unroll
    for (int ni = 0; ni < 4; ++ni)
      #pragma unroll
      for (int rr = 0; rr < 16; ++rr) {
        const int row = mt * 64 + w * 32 + (rr & 3) + 8 * (rr >> 2) + 4 * q2;
        atomicAdd(out + ((size_t)b * 2048 + row) * 128 + ni * 32 + l31,
                  acc[ni][rr]);
      }
  }
}

// ---------------------------------------------------------------------------
// Reduce: out = sum over 8 ksp partial slices (zg pre-scaled by 1/128).
// ---------------------------------------------------------------------------
__global__ __launch_bounds__(256) void reduce_kernel(
    const float* __restrict__ partials, float* __restrict__ out)
{
  const size_t base = ((size_t)blockIdx.x * 256 + threadIdx.x) * 4;
  const float* p = partials + base;
  f32x4 s = *(const f32x4*)p;
  #pragma unroll
  for (int ksv = 1; ksv < 8; ++ksv) {
    f32x4 v = *(const f32x4*)(p + (size_t)ksv * 1048576);
    s.x += v.x; s.y += v.y; s.z += v.z; s.w += v.w;
  }
  *(f32x4*)(out + base) = s;
}

// ---------------------------------------------------------------------------
extern "C" void kernel_launch(void* const* d_in, const int* in_sizes, int n_in,
                              void* d_out, int out_size, void* d_ws, size_t ws_size,
                              hipStream_t stream) {
  const float* x_grid = (const float*)d_in[0];   // (4,128,128,2)
  const float* z_grid = (const float*)d_in[1];   // (4,128,128,128)
  const float* xt     = (const float*)d_in[2];   // (4,2048,2)
  const float* lsp    = (const float*)d_in[3];   // (2,)
  float* out = (float*)d_out;                    // (4,2048,128) f32

  char* ws = (char*)d_ws;
  unsigned short* zgb = (unsigned short*)ws;                   // 16 MB
  float* xg_trip = (float*)(ws + 16777216);                    // 768 KB
  float* xt4     = (float*)(ws + 16777216 + 786432);           // 128 KB
  const size_t poff = 16777216 + 786432 + 131072;              // 17694720
  const bool use_partials = ws_size >= poff + 33554432;        // +32 MB
  float* partials = use_partials ? (float*)(ws + poff) : nullptr;

  if (!use_partials)
    hipMemsetAsync(d_out, 0, (size_t)out_size * sizeof(float), stream);
  pre_kernel<<<1024, 256, 0, stream>>>(x_grid, z_grid, xt, lsp,
                                       zgb, xg_trip, xt4);
  main_kernel<<<1024, 128, 0, stream>>>(zgb, xg_trip, xt4, out, partials);
  if (use_partials)
    reduce_kernel<<<1024, 256, 0, stream>>>(partials, out);
}